// Round 1
// baseline (150.115 us; speedup 1.0000x reference)
//
#include <hip/hip_runtime.h>

// SAR quantizer: q, Q, Wn outputs.
// L=524288 rows, A=24 ADCs, B=8 bits, M=36 coefficient rows.
// VR = VREF = 1.8 / 2^3 = 0.225, noise scale = 0.01**0.5 = 0.1.

#define L_TOT   524288
#define A_ADC   24
#define M_ROWS  36
#define B_BITS  8

__global__ __launch_bounds__(192) void sar_kernel(
    const float* __restrict__ x,
    const float* __restrict__ W,
    const float* __restrict__ nz,
    float* __restrict__ out_q,
    float* __restrict__ out_Q,
    float* __restrict__ out_Wn,
    long long N)
{
    const long long gid = (long long)blockIdx.x * blockDim.x + threadIdx.x;
    const long long T   = (long long)gridDim.x * blockDim.x;  // multiple of 24
    const int a = (int)(gid % 24);   // fixed ADC column for this thread

    // Per-a coefficients: c[r] = (W[r][a] + noise[r][a]*0.1f) * 0.225f
    // Same rounding sequence as reference (Wn then Wn*VR). 36 regs.
    float c[M_ROWS];
#pragma unroll
    for (int r = 0; r < M_ROWS; ++r) {
        float wn = W[r * A_ADC + a] + nz[r * A_ADC + a] * 0.1f;
        c[r] = wn * 0.225f;
    }

    // Wn tail output (864 floats), once, deterministic.
    if (gid < (long long)(M_ROWS * A_ADC)) {
        out_Wn[gid] = W[gid] + nz[gid] * 0.1f;
    }

    for (long long i = gid; i < N; i += T) {
        const float xv = x[i];
        float q[B_BITS];

        // Bit-serial SAR, fully unrolled; m indices are compile-time.
        int m = M_ROWS - 1;
#pragma unroll
        for (int jj = 0; jj < B_BITS; ++jj) {
            const int j = B_BITS - 1 - jj;
            float bs = c[m]; --m;          // Wn[m]*VREF
#pragma unroll
            for (int k = j + 1; k < B_BITS; ++k) {
                // (q_k + 1)*0.5 in {0, 0.5, 1} -> product exact; add in
                // the same k-ascending order as the reference.
                float t = (q[k] + 1.0f) * 0.5f;
                bs += t * c[m];
                --m;
            }
            float s = (xv - bs) + 1e-30f;
            q[j] = (s > 0.0f) ? 1.0f : ((s < 0.0f) ? -1.0f : 0.0f);
        }

        // q = sum_j (q_j+1)/2 * (0.225 * 2^j), ascending j
        float acc = 0.0f;
#pragma unroll
        for (int j = 0; j < B_BITS; ++j) {
            float t = (q[j] + 1.0f) * 0.5f;
            float bwj = 0.225f * (float)(1 << j);  // exact pow2 scaling
            acc += t * bwj;
        }
        out_q[i] = acc;

        // Q[l][a][0..7]: 8 contiguous floats -> two float4 stores (32B/lane,
        // contiguous 2KB per wave64).
        float4* Qp = (float4*)(out_Q + i * 8);
        Qp[0] = make_float4(q[0], q[1], q[2], q[3]);
        Qp[1] = make_float4(q[4], q[5], q[6], q[7]);
    }
}

extern "C" void kernel_launch(void* const* d_in, const int* in_sizes, int n_in,
                              void* d_out, int out_size, void* d_ws, size_t ws_size,
                              hipStream_t stream) {
    const float* x  = (const float*)d_in[0];
    const float* W  = (const float*)d_in[1];
    const float* nz = (const float*)d_in[2];
    float* out = (float*)d_out;

    const long long N = (long long)L_TOT * A_ADC;   // 12,582,912
    float* out_q  = out;
    float* out_Q  = out + N;
    float* out_Wn = out + N + N * (long long)B_BITS;

    // 2048 blocks x 192 threads: stride = 393216 (multiple of 24),
    // exactly 32 grid-stride iterations; 3 waves/block.
    sar_kernel<<<2048, 192, 0, stream>>>(x, W, nz, out_q, out_Q, out_Wn, N);
}

// Round 2
// 132.436 us; speedup vs baseline: 1.1335x; 1.1335x over previous
//
#include <hip/hip_runtime.h>

// SAR quantizer: q, Q, Wn outputs.
// L=524288 rows, A=24 ADCs, B=8 bits, M=36 coefficient rows.
// VR = VREF = 1.8 / 2^3 = 0.225, noise scale = 0.01**0.5 = 0.1.
//
// R2 change: Q writes staged through LDS per-wave (2KB tiles) so each
// global store instruction covers a dense, contiguous 1KB — the previous
// direct two-dwordx4-per-lane pattern half-covered every 64B line per
// instruction (suspected partial-line write inefficiency, ~2x on 80% of
// the traffic).

#define L_TOT   524288
#define A_ADC   24
#define M_ROWS  36
#define B_BITS  8

// XOR bank-quad swizzle (involution, bijective on [0,128)):
// spreads both the per-lane write pattern (chunks 2l,2l+1) and the
// flush read pattern (chunks s*64+l) across all 8 bank-quads.
__device__ __forceinline__ int swz(int c) { return c ^ ((c >> 3) & 7); }

__global__ __launch_bounds__(192) void sar_kernel(
    const float* __restrict__ x,
    const float* __restrict__ W,
    const float* __restrict__ nz,
    float* __restrict__ out_q,
    float* __restrict__ out_Q,
    float* __restrict__ out_Wn,
    long long N)
{
    const long long gid = (long long)blockIdx.x * blockDim.x + threadIdx.x;
    const long long T   = (long long)gridDim.x * blockDim.x;  // multiple of 24
    const int a = (int)(gid % 24);   // fixed ADC column for this thread
    const int w = threadIdx.x >> 6;  // wave id in block (0..2)
    const int l = threadIdx.x & 63;  // lane

    __shared__ float4 stage[3][128]; // 2KB per wave, wave-private

    // Per-a coefficients: c[r] = (W[r][a] + noise[r][a]*0.1f) * 0.225f
    // Same rounding sequence as reference (Wn then Wn*VR). 36 regs.
    float c[M_ROWS];
#pragma unroll
    for (int r = 0; r < M_ROWS; ++r) {
        float wn = W[r * A_ADC + a] + nz[r * A_ADC + a] * 0.1f;
        c[r] = wn * 0.225f;
    }

    // Wn tail output (864 floats), once, deterministic.
    if (gid < (long long)(M_ROWS * A_ADC)) {
        out_Wn[gid] = W[gid] + nz[gid] * 0.1f;
    }

    for (long long i = gid; i < N; i += T) {
        const float xv = x[i];
        float q[B_BITS];

        // Bit-serial SAR, fully unrolled; m indices are compile-time.
        int m = M_ROWS - 1;
#pragma unroll
        for (int jj = 0; jj < B_BITS; ++jj) {
            const int j = B_BITS - 1 - jj;
            float bs = c[m]; --m;          // Wn[m]*VREF
#pragma unroll
            for (int k = j + 1; k < B_BITS; ++k) {
                // (q_k + 1)*0.5 in {0, 0.5, 1} -> product exact; add in
                // the same k-ascending order as the reference.
                float t = (q[k] + 1.0f) * 0.5f;
                bs += t * c[m];
                --m;
            }
            float s = (xv - bs) + 1e-30f;
            q[j] = (s > 0.0f) ? 1.0f : ((s < 0.0f) ? -1.0f : 0.0f);
        }

        // q = sum_j (q_j+1)/2 * (0.225 * 2^j), ascending j
        float acc = 0.0f;
#pragma unroll
        for (int j = 0; j < B_BITS; ++j) {
            float t = (q[j] + 1.0f) * 0.5f;
            float bwj = 0.225f * (float)(1 << j);  // exact pow2 scaling
            acc += t * bwj;
        }
        out_q[i] = acc;

        // --- Q output via LDS staging ---
        // Wave's 64 consecutive elements form a dense 2KB region of Q.
        // Stage this lane's 8 floats (chunks 2l, 2l+1), then flush with
        // two instructions each covering a contiguous 1KB.
        const int c0 = 2 * l, c1 = 2 * l + 1;
        stage[w][swz(c0)] = make_float4(q[0], q[1], q[2], q[3]);
        stage[w][swz(c1)] = make_float4(q[4], q[5], q[6], q[7]);
        // wave-private region: no barrier needed; compiler inserts lgkmcnt.
        const long long base_w = i - l;              // wave's first element
        float4* Qw = (float4*)(out_Q + base_w * 8);  // float4 index space
        const int r0 = l, r1 = 64 + l;
        Qw[r0] = stage[w][swz(r0)];
        Qw[r1] = stage[w][swz(r1)];
    }
}

extern "C" void kernel_launch(void* const* d_in, const int* in_sizes, int n_in,
                              void* d_out, int out_size, void* d_ws, size_t ws_size,
                              hipStream_t stream) {
    const float* x  = (const float*)d_in[0];
    const float* W  = (const float*)d_in[1];
    const float* nz = (const float*)d_in[2];
    float* out = (float*)d_out;

    const long long N = (long long)L_TOT * A_ADC;   // 12,582,912
    float* out_q  = out;
    float* out_Q  = out + N;
    float* out_Wn = out + N + N * (long long)B_BITS;

    // 2048 blocks x 192 threads: stride = 393216 (multiple of 24),
    // exactly 32 grid-stride iterations; 3 waves/block.
    sar_kernel<<<2048, 192, 0, stream>>>(x, W, nz, out_q, out_Q, out_Wn, N);
}